// Round 11
// baseline (86504.578 us; speedup 1.0000x reference)
//
#include <hip/hip_runtime.h>

#define BB 128
#define TT 512
#define DD 256
#define HH 512

__device__ __forceinline__ float sig_(float x) { return 1.0f / (1.0f + __expf(-x)); }

#define FMA4(ACC, AV, WV)                     \
  do {                                        \
    ACC[0] = fmaf((AV), (WV).x, ACC[0]);      \
    ACC[1] = fmaf((AV), (WV).y, ACC[1]);      \
    ACC[2] = fmaf((AV), (WV).z, ACC[2]);      \
    ACC[3] = fmaf((AV), (WV).w, ACC[3]);      \
  } while (0)

// Persistent c-state across per-phase launches (r8-proven pattern).
__device__ float g_c[2 * BB * HH];

// Packed weights: [role][cell][k4][kk*4+gate], contiguous 16 floats per k4.
// role0: 512 cells x 192 k4 x 16 = 1,572,864 floats
// role1: 512 cells x 256 k4 x 16 = 2,097,152 floats
// 14.7 MB device-global (zero ws growth). Written once per launch by pack_w.
#define W0_CELL 3072   // floats per cell, role 0 (768 k x 4 gates)
#define W1_CELL 4096   // floats per cell, role 1 (1024 k x 4 gates)
#define W1_BASE (512 * W0_CELL)
__device__ float g_w[512 * W0_CELL + 512 * W1_CELL];

// ---------------- projection GEMM: xp = x @ proj_w.T + proj_b ----------------
// (unchanged, known-good)
__global__ __launch_bounds__(256) void proj_kernel(const float* __restrict__ x,
                                                   const float* __restrict__ pw,
                                                   const float* __restrict__ pb,
                                                   float* __restrict__ xp) {
  __shared__ float At[64 * 68];
  __shared__ float Bt[64 * 68];
  const int bm = blockIdx.x >> 2;
  const int bn = blockIdx.x & 3;
  const int tid = threadIdx.x;
  const int rg = tid >> 4;
  const int cgi = tid & 15;
  const int m0 = bm * 64, n0 = bn * 64;
  float acc[4][4] = {};
  for (int kt = 0; kt < 4; ++kt) {
    const int k0 = kt * 64;
    {
      const int r = tid >> 2, q = tid & 3;
      const float4* src = (const float4*)(x + (size_t)(m0 + r) * DD + k0 + q * 16);
      float4* dst = (float4*)&At[r * 68 + q * 16];
#pragma unroll
      for (int j = 0; j < 4; ++j) dst[j] = src[j];
    }
    {
      const int n = tid & 63, kg = tid >> 6;
      const float4* src = (const float4*)(pw + (size_t)(n0 + n) * DD + k0 + kg * 16);
#pragma unroll
      for (int j = 0; j < 4; ++j) {
        float4 v = src[j];
        const int kk = kg * 16 + j * 4;
        Bt[(kk + 0) * 68 + n] = v.x;
        Bt[(kk + 1) * 68 + n] = v.y;
        Bt[(kk + 2) * 68 + n] = v.z;
        Bt[(kk + 3) * 68 + n] = v.w;
      }
    }
    __syncthreads();
#pragma unroll
    for (int k4 = 0; k4 < 64; k4 += 4) {
      float4 a[4], b[4];
#pragma unroll
      for (int j = 0; j < 4; ++j) a[j] = *(const float4*)&At[(rg * 4 + j) * 68 + k4];
#pragma unroll
      for (int j = 0; j < 4; ++j) b[j] = *(const float4*)&Bt[(k4 + j) * 68 + cgi * 4];
#pragma unroll
      for (int jr = 0; jr < 4; ++jr) {
        FMA4(acc[jr], a[jr].x, b[0]);
        FMA4(acc[jr], a[jr].y, b[1]);
        FMA4(acc[jr], a[jr].z, b[2]);
        FMA4(acc[jr], a[jr].w, b[3]);
      }
    }
    __syncthreads();
  }
  const float4 bias = *(const float4*)&pb[n0 + cgi * 4];
#pragma unroll
  for (int jr = 0; jr < 4; ++jr) {
    float4 o;
    o.x = acc[jr][0] + bias.x;
    o.y = acc[jr][1] + bias.y;
    o.z = acc[jr][2] + bias.z;
    o.w = acc[jr][3] + bias.w;
    *(float4*)&xp[(size_t)(m0 + rg * 4 + jr) * DD + n0 + cgi * 4] = o;
  }
}

// ---------------- weight pack: g_w[role][cell][k4][kk*4+g] ------------------
// One launch, 1024 blocks x 256 threads. Coalesced reads (lane l reads bytes
// 16l..16l+16 of a gate row) and coalesced 64B/lane writes.
__global__ __launch_bounds__(256) void pack_w(
    const float* __restrict__ wx0, const float* __restrict__ wh0,
    const float* __restrict__ wx1, const float* __restrict__ wh1) {
  const int role = blockIdx.x >> 9;
  const int c = blockIdx.x & 511;
  const int KX = role ? HH : DD;
  const int nk4 = (KX + HH) >> 2;  // 192 or 256
  const float* __restrict__ wx = role ? wx1 : wx0;
  const float* __restrict__ wh = role ? wh1 : wh0;
  float* __restrict__ dst =
      g_w + (role ? (W1_BASE + (size_t)c * W1_CELL) : ((size_t)c * W0_CELL));
  for (int k4 = threadIdx.x; k4 < nk4; k4 += 256) {
    const int k = k4 << 2;
#pragma unroll
    for (int g = 0; g < 4; ++g) {
      const int row = g * HH + c;
      float4 v;
      if (k < KX) v = *(const float4*)(wx + (size_t)row * KX + k);
      else        v = *(const float4*)(wh + (size_t)row * HH + (k - KX));
      dst[k4 * 16 + 0 * 4 + g] = v.x;
      dst[k4 * 16 + 1 * 4 + g] = v.y;
      dst[k4 * 16 + 2 * 4 + g] = v.z;
      dst[k4 * 16 + 3 * 4 + g] = v.w;
    }
  }
}

// ---------------- per-phase 2-layer LSTM step -------------------------------
// r8 structure (proven 36.4ms, absmax 0.0): 513 launches, 256 blocks x 256
// threads, kernel boundaries = grid barrier. ONE CHANGE vs r8: W reads come
// from the packed GLOBAL array (L2-resident, VMEM pipe) instead of LDS.
// This removes the 16-lane-broadcast ds_reads (4 of 6 per k4) from the LDS
// port: inner-loop LDS wave-insts/CU/phase 6144 -> 2048. Values and FMA
// order are bit-identical to r8.

// --- A-tile reg staging: 8 x float4 per thread (128 rows x 64 k per tile) ---
__device__ __forceinline__ void load_plain(float4 (&R)[8], const float* base,
                                           size_t rs, int trb, int gq) {
#pragma unroll
  for (int j = 0; j < 8; ++j)
    R[j] = *(const float4*)(base + (size_t)(j * 16 + trb) * rs + (gq << 2));
}

// LDS A layout: row r, granule g stored at r*64 + (g ^ ((r>>1)&7))*4. (r8)
__device__ __forceinline__ void write_tile(float* Abuf, const float4 (&R)[8],
                                           int trb, int wp_) {
#pragma unroll
  for (int j = 0; j < 8; ++j)
    *(float4*)&Abuf[(j * 16 + trb) * 64 + (wp_ << 2)] = R[j];
}

__device__ __forceinline__ void compute_tile(float acc0[4], float acc1[4],
                                             const float* Abuf,
                                             const float* __restrict__ wt,
                                             int rowg) {
  const float* Ar = Abuf + rowg * 128;
  const int rsw = rowg & 7;
#pragma unroll
  for (int k4 = 0; k4 < 64; k4 += 4) {
    const int off = (((k4 >> 2) ^ rsw) << 2);
    const float4 a0 = *(const float4*)(Ar + off);        // row 2*rowg
    const float4 a1 = *(const float4*)(Ar + 64 + off);   // row 2*rowg+1
    const float* wp = wt + (k4 << 2);  // packed: 16 floats per k4-block
    const float4 w0 = *(const float4*)(wp + 0);   // gates i,f,g,o @ k4+0
    const float4 w1 = *(const float4*)(wp + 4);   // @ k4+1
    const float4 w2 = *(const float4*)(wp + 8);   // @ k4+2
    const float4 w3 = *(const float4*)(wp + 12);  // @ k4+3
    FMA4(acc0, a0.x, w0);
    FMA4(acc0, a0.y, w1);
    FMA4(acc0, a0.z, w2);
    FMA4(acc0, a0.w, w3);
    FMA4(acc1, a1.x, w0);
    FMA4(acc1, a1.y, w1);
    FMA4(acc1, a1.z, w2);
    FMA4(acc1, a1.w, w3);
  }
}

__global__ __launch_bounds__(256, 1) void lstm_phase(
    const float* __restrict__ xp,
    const float* __restrict__ bx0, const float* __restrict__ bh0,
    const float* __restrict__ bx1, const float* __restrict__ bh1,
    float* __restrict__ h0buf, float* __restrict__ h1buf, int p) {
  __shared__ float Ab[2][8192];  // A tiles, swizzled (2 x 32 KB)

  const int bidx = blockIdx.x;
  const int role = bidx >> 7;  // 0: layer0, 1: layer1
  const bool active = role ? (p >= 1) : (p < TT);
  if (!active) return;

  const int bj = bidx & 127;   // cell-slice: cells bj*4 .. bj*4+3
  const int tid = threadIdx.x;
  const int cell = tid & 3;
  const int rowg = tid >> 2;   // rows rowg*2, rowg*2+1
  const int trb = tid >> 4;    // staging row base
  const int gq = tid & 15;     // staging granule
  const int wp_ = gq ^ ((trb >> 1) & 7);  // swizzled write position
  const int cell_g = bj * 4 + cell;

  const float* __restrict__ bxv = role ? bx1 : bx0;
  const float* __restrict__ bhv = role ? bh1 : bh0;
  const int KX = role ? HH : DD;   // K of the "x" operand
  const int nt = (KX + HH) >> 6;   // 12 (L0) or 16 (L1) K-tiles

  // packed W base for this thread's cell; per tile kt: + kt*256 floats
  const float* __restrict__ wbase =
      g_w + (role ? (W1_BASE + (size_t)cell_g * W1_CELL)
                  : ((size_t)cell_g * W0_CELL));

  float bg[4];
#pragma unroll
  for (int g = 0; g < 4; ++g)
    bg[g] = bxv[(size_t)g * HH + cell_g] + bhv[(size_t)g * HH + cell_g];

  const int t = role ? (p - 1) : p;
  const int rd = (p + 1) & 1;  // buffer written during phase p-1
  const int wr = p & 1;
  const float* __restrict__ h0rd = h0buf + (size_t)rd * BB * HH;
  const float* __restrict__ h1rd = h1buf + (size_t)rd * BB * HH;
  float* __restrict__ hout = (role ? h1buf : h0buf) + (size_t)wr * BB * HH;

  // c-state: first step of this layer starts from 0
  const bool first = role ? (p == 1) : (p == 0);
  float cst0, cst1;
  {
    float* c0 = &g_c[((size_t)role * BB + rowg * 2 + 0) * HH + cell_g];
    float* c1 = &g_c[((size_t)role * BB + rowg * 2 + 1) * HH + cell_g];
    cst0 = first ? 0.0f : *c0;
    cst1 = first ? 0.0f : *c1;
  }

  float acc0[4] = {0.f, 0.f, 0.f, 0.f};
  float acc1[4] = {0.f, 0.f, 0.f, 0.f};

  auto srcload = [&](float4(&R)[8], int kt) {
    if (role == 0) {
      if (kt < 4)
        load_plain(R, xp + (size_t)t * DD + kt * 64, (size_t)TT * DD, trb, gq);
      else
        load_plain(R, h0rd + (kt - 4) * 64, (size_t)HH, trb, gq);
    } else {
      if (kt < 8) load_plain(R, h0rd + kt * 64, (size_t)HH, trb, gq);
      else        load_plain(R, h1rd + (kt - 8) * 64, (size_t)HH, trb, gq);
    }
  };

  float4 ra[8], rb4[8];
  srcload(ra, 0);
#pragma unroll 1
  for (int kt = 0; kt < nt; kt += 2) {  // nt is even (12 or 16)
    srcload(rb4, kt + 1);
    __syncthreads();                 // buf0 readers (prev iter) done
    write_tile(Ab[0], ra, trb, wp_);
    __syncthreads();
    compute_tile(acc0, acc1, Ab[0], wbase + (size_t)kt * 256, rowg);
    if (kt + 2 < nt) srcload(ra, kt + 2);
    __syncthreads();                 // buf1 readers done
    write_tile(Ab[1], rb4, trb, wp_);
    __syncthreads();
    compute_tile(acc0, acc1, Ab[1], wbase + (size_t)(kt + 1) * 256, rowg);
  }

  // ---- cell update + h store (plain; kernel boundary publishes) ----
  {
    float iv = acc0[0] + bg[0], fv = acc0[1] + bg[1];
    float gv = acc0[2] + bg[2], ov = acc0[3] + bg[3];
    float cn = sig_(fv) * cst0 + sig_(iv) * tanhf(gv);
    g_c[((size_t)role * BB + rowg * 2 + 0) * HH + cell_g] = cn;
    hout[(size_t)(rowg * 2 + 0) * HH + cell_g] = sig_(ov) * tanhf(cn);
    iv = acc1[0] + bg[0]; fv = acc1[1] + bg[1];
    gv = acc1[2] + bg[2]; ov = acc1[3] + bg[3];
    cn = sig_(fv) * cst1 + sig_(iv) * tanhf(gv);
    g_c[((size_t)role * BB + rowg * 2 + 1) * HH + cell_g] = cn;
    hout[(size_t)(rowg * 2 + 1) * HH + cell_g] = sig_(ov) * tanhf(cn);
  }
}

// ---------------- head: out = relu(h1 @ fc1.T + b1) @ fc2.T + b2 ------------
__global__ __launch_bounds__(256) void head_kernel(const float* __restrict__ h1,
                                                   const float* __restrict__ fc1w,
                                                   const float* __restrict__ fc1b,
                                                   const float* __restrict__ fc2w,
                                                   const float* __restrict__ fc2b,
                                                   float* __restrict__ out) {
  __shared__ float part[256];
  __shared__ float hid[32];
  const int r = blockIdx.x;
  const int tid = threadIdx.x;
  const int c = tid & 31, pt = tid >> 5;
  const float4* ha = (const float4*)(h1 + (size_t)r * HH + pt * 64);
  const float4* wa = (const float4*)(fc1w + (size_t)c * HH + pt * 64);
  float s = 0.f;
#pragma unroll
  for (int j = 0; j < 16; ++j) {
    float4 av = ha[j], wv = wa[j];
    s = fmaf(av.x, wv.x, s);
    s = fmaf(av.y, wv.y, s);
    s = fmaf(av.z, wv.z, s);
    s = fmaf(av.w, wv.w, s);
  }
  part[tid] = s;
  __syncthreads();
  if (tid < 32) {
    float v = fc1b[tid];
#pragma unroll
    for (int q = 0; q < 8; ++q) v += part[q * 32 + tid];
    hid[tid] = fmaxf(v, 0.f);
  }
  __syncthreads();
  if (tid == 0) {
    float v = fc2b[0];
    for (int cc = 0; cc < 32; ++cc) v = fmaf(hid[cc], fc2w[cc], v);
    out[r] = v;
  }
}

extern "C" void kernel_launch(void* const* d_in, const int* in_sizes, int n_in,
                              void* d_out, int out_size, void* d_ws, size_t ws_size,
                              hipStream_t stream) {
  const float* x    = (const float*)d_in[0];
  const float* pw   = (const float*)d_in[1];
  const float* pb   = (const float*)d_in[2];
  const float* wx0  = (const float*)d_in[3];
  const float* bx0  = (const float*)d_in[4];
  const float* wh0  = (const float*)d_in[5];
  const float* bh0  = (const float*)d_in[6];
  const float* wx1  = (const float*)d_in[7];
  const float* bx1  = (const float*)d_in[8];
  const float* wh1  = (const float*)d_in[9];
  const float* bh1  = (const float*)d_in[10];
  const float* fc1w = (const float*)d_in[11];
  const float* fc1b = (const float*)d_in[12];
  const float* fc2w = (const float*)d_in[13];
  const float* fc2b = (const float*)d_in[14];
  float* out = (float*)d_out;

  // ws layout (floats): xp [B*T*D] | h0buf [2*B*H] | h1buf [2*B*H]
  // — EXACTLY the round-0/1/8 proven footprint, nothing appended.
  float* xp = (float*)d_ws;
  float* h0buf = xp + (size_t)BB * TT * DD;
  float* h1buf = h0buf + 2 * BB * HH;

  // zero initial h state (both buffers, both slots; 1 MB, stream-ordered)
  hipMemsetAsync(h0buf, 0, (size_t)4 * BB * HH * sizeof(float), stream);

  pack_w<<<dim3(1024), dim3(256), 0, stream>>>(wx0, wh0, wx1, wh1);
  proj_kernel<<<dim3(4096), dim3(256), 0, stream>>>(x, pw, pb, xp);

  // 513 per-phase launches: kernel boundaries = grid barrier + coherence.
  for (int p = 0; p <= TT; ++p) {
    lstm_phase<<<dim3(256), dim3(256), 0, stream>>>(
        xp, bx0, bh0, bx1, bh1, h0buf, h1buf, p);
  }

  // final h1 lives in buffer index (512 & 1) == 0
  head_kernel<<<dim3(BB), dim3(256), 0, stream>>>(h1buf, fc1w, fc1b, fc2w, fc2b, out);
}

// Round 12
// 37123.370 us; speedup vs baseline: 2.3302x; 2.3302x over previous
//
#include <hip/hip_runtime.h>

#define BB 128
#define TT 512
#define DD 256
#define HH 512

__device__ __forceinline__ float sig_(float x) { return 1.0f / (1.0f + __expf(-x)); }

#define FMA4(ACC, AV, WV)                     \
  do {                                        \
    ACC[0] = fmaf((AV), (WV).x, ACC[0]);      \
    ACC[1] = fmaf((AV), (WV).y, ACC[1]);      \
    ACC[2] = fmaf((AV), (WV).z, ACC[2]);      \
    ACC[3] = fmaf((AV), (WV).w, ACC[3]);      \
  } while (0)

// Persistent c-state across per-phase launches (r8-proven pattern).
__device__ float g_c[2 * BB * HH];

// Pre-packed W in the EXACT Wl LDS layout per lstm block: [k][16 cols],
// pitch 16 (col = local_cell*4 + gate). Packed once per launch by pack_w;
// each phase then stages W with a linear float4 copy (coalesced loads,
// conflict-free b128 LDS writes) instead of r8's strided scalar transform.
// role0 block: 768*16 = 12288 floats; role1 block: 1024*16 = 16384 floats.
#define W0_BLK 12288
#define W1_BLK 16384
#define W1_BASE (128 * W0_BLK)
__device__ float g_w[128 * W0_BLK + 128 * W1_BLK];  // 14.7 MB

// ---------------- projection GEMM: xp = x @ proj_w.T + proj_b ----------------
// (unchanged, known-good)
__global__ __launch_bounds__(256) void proj_kernel(const float* __restrict__ x,
                                                   const float* __restrict__ pw,
                                                   const float* __restrict__ pb,
                                                   float* __restrict__ xp) {
  __shared__ float At[64 * 68];
  __shared__ float Bt[64 * 68];
  const int bm = blockIdx.x >> 2;
  const int bn = blockIdx.x & 3;
  const int tid = threadIdx.x;
  const int rg = tid >> 4;
  const int cgi = tid & 15;
  const int m0 = bm * 64, n0 = bn * 64;
  float acc[4][4] = {};
  for (int kt = 0; kt < 4; ++kt) {
    const int k0 = kt * 64;
    {
      const int r = tid >> 2, q = tid & 3;
      const float4* src = (const float4*)(x + (size_t)(m0 + r) * DD + k0 + q * 16);
      float4* dst = (float4*)&At[r * 68 + q * 16];
#pragma unroll
      for (int j = 0; j < 4; ++j) dst[j] = src[j];
    }
    {
      const int n = tid & 63, kg = tid >> 6;
      const float4* src = (const float4*)(pw + (size_t)(n0 + n) * DD + k0 + kg * 16);
#pragma unroll
      for (int j = 0; j < 4; ++j) {
        float4 v = src[j];
        const int kk = kg * 16 + j * 4;
        Bt[(kk + 0) * 68 + n] = v.x;
        Bt[(kk + 1) * 68 + n] = v.y;
        Bt[(kk + 2) * 68 + n] = v.z;
        Bt[(kk + 3) * 68 + n] = v.w;
      }
    }
    __syncthreads();
#pragma unroll
    for (int k4 = 0; k4 < 64; k4 += 4) {
      float4 a[4], b[4];
#pragma unroll
      for (int j = 0; j < 4; ++j) a[j] = *(const float4*)&At[(rg * 4 + j) * 68 + k4];
#pragma unroll
      for (int j = 0; j < 4; ++j) b[j] = *(const float4*)&Bt[(k4 + j) * 68 + cgi * 4];
#pragma unroll
      for (int jr = 0; jr < 4; ++jr) {
        FMA4(acc[jr], a[jr].x, b[0]);
        FMA4(acc[jr], a[jr].y, b[1]);
        FMA4(acc[jr], a[jr].z, b[2]);
        FMA4(acc[jr], a[jr].w, b[3]);
      }
    }
    __syncthreads();
  }
  const float4 bias = *(const float4*)&pb[n0 + cgi * 4];
#pragma unroll
  for (int jr = 0; jr < 4; ++jr) {
    float4 o;
    o.x = acc[jr][0] + bias.x;
    o.y = acc[jr][1] + bias.y;
    o.z = acc[jr][2] + bias.z;
    o.w = acc[jr][3] + bias.w;
    *(float4*)&xp[(size_t)(m0 + rg * 4 + jr) * DD + n0 + cgi * 4] = o;
  }
}

// ---------------- weight pack (once per launch) ------------------------------
// 256 blocks x 256 threads; block b packs lstm-block b's W slice using the
// exact index transform r8 used for its per-phase staging.
__global__ __launch_bounds__(256) void pack_w(
    const float* __restrict__ wx0, const float* __restrict__ wh0,
    const float* __restrict__ wx1, const float* __restrict__ wh1) {
  const int role = blockIdx.x >> 7;
  const int bj = blockIdx.x & 127;
  const int tid = threadIdx.x;
  const int KX = role ? HH : DD;
  const float* __restrict__ wx = role ? wx1 : wx0;
  const float* __restrict__ wh = role ? wh1 : wh0;
  float* __restrict__ dst =
      g_w + (role ? (W1_BASE + (size_t)bj * W1_BLK) : ((size_t)bj * W0_BLK));
  const int col = tid & 15, part = tid >> 4;
  const int lc = col >> 2, g = col & 3;
  const int grow = g * HH + bj * 4 + lc;  // global gate row 0..2047
  const int span = (KX + HH) >> 4;        // 48 or 64 k per thread
  const int k0 = part * span;
  for (int k = k0; k < k0 + span; k += 4) {
    float4 v;
    if (k < KX) v = *(const float4*)(wx + (size_t)grow * KX + k);
    else        v = *(const float4*)(wh + (size_t)grow * HH + (k - KX));
    dst[(k + 0) * 16 + col] = v.x;
    dst[(k + 1) * 16 + col] = v.y;
    dst[(k + 2) * 16 + col] = v.z;
    dst[(k + 3) * 16 + col] = v.w;
  }
}

// ---------------- per-phase 2-layer LSTM step -------------------------------
// r8 structure (proven 36.4ms / absmax 0.0): 513 launches, 256 blocks x 256
// threads, 1 block/CU, kernel boundaries = grid barrier. Three safe deltas:
// (1) W staged via linear float4 copy from pre-packed g_w (was strided
//     scalar transform, ~5-7us of serialized prologue);
// (2) 2 syncthreads per 2 tiles (was 4): ds_writes of one buffer overlap
//     compute of the other;
// (3) first A-tile load issued before the W copy (latency overlap).
// compute_tile, swizzle, accumulation order: byte-identical to r8.

// --- A-tile reg staging: 8 x float4 per thread (128 rows x 64 k per tile) ---
__device__ __forceinline__ void load_plain(float4 (&R)[8], const float* base,
                                           size_t rs, int trb, int gq) {
#pragma unroll
  for (int j = 0; j < 8; ++j)
    R[j] = *(const float4*)(base + (size_t)(j * 16 + trb) * rs + (gq << 2));
}

// LDS A layout: row r, granule g stored at r*64 + (g ^ ((r>>1)&7))*4. (r8)
__device__ __forceinline__ void write_tile(float* Abuf, const float4 (&R)[8],
                                           int trb, int wp_) {
#pragma unroll
  for (int j = 0; j < 8; ++j)
    *(float4*)&Abuf[(j * 16 + trb) * 64 + (wp_ << 2)] = R[j];
}

__device__ __forceinline__ void compute_tile(float acc0[4], float acc1[4],
                                             const float* Abuf, const float* Wl,
                                             int kt, int rowg, int cell) {
  const float* Wt = Wl + (kt << 10) + (cell << 2);
  const float* Ar = Abuf + rowg * 128;
  const int rsw = rowg & 7;
#pragma unroll
  for (int k4 = 0; k4 < 64; k4 += 4) {
    const int off = (((k4 >> 2) ^ rsw) << 2);
    const float4 a0 = *(const float4*)(Ar + off);        // row 2*rowg
    const float4 a1 = *(const float4*)(Ar + 64 + off);   // row 2*rowg+1
    const float* wp = Wt + (k4 << 4);
    const float4 w0 = *(const float4*)(wp + 0);
    const float4 w1 = *(const float4*)(wp + 16);
    const float4 w2 = *(const float4*)(wp + 32);
    const float4 w3 = *(const float4*)(wp + 48);
    FMA4(acc0, a0.x, w0);
    FMA4(acc0, a0.y, w1);
    FMA4(acc0, a0.z, w2);
    FMA4(acc0, a0.w, w3);
    FMA4(acc1, a1.x, w0);
    FMA4(acc1, a1.y, w1);
    FMA4(acc1, a1.z, w2);
    FMA4(acc1, a1.w, w3);
  }
}

__global__ __launch_bounds__(256, 1) void lstm_phase(
    const float* __restrict__ xp,
    const float* __restrict__ bx0, const float* __restrict__ bh0,
    const float* __restrict__ bx1, const float* __restrict__ bh1,
    float* __restrict__ h0buf, float* __restrict__ h1buf, int p) {
  __shared__ float Wl[16384];    // W slice [k][16 cols], pitch 16 (64 KB)
  __shared__ float Ab[2][8192];  // A tiles, swizzled (2 x 32 KB)

  const int bidx = blockIdx.x;
  const int role = bidx >> 7;  // 0: layer0, 1: layer1
  const bool active = role ? (p >= 1) : (p < TT);
  if (!active) return;

  const int bj = bidx & 127;   // cell-slice: cells bj*4 .. bj*4+3
  const int tid = threadIdx.x;
  const int cell = tid & 3;
  const int rowg = tid >> 2;   // rows rowg*2, rowg*2+1
  const int trb = tid >> 4;    // staging row base
  const int gq = tid & 15;     // staging granule
  const int wp_ = gq ^ ((trb >> 1) & 7);  // swizzled write position
  const int cell_g = bj * 4 + cell;

  const float* __restrict__ bxv = role ? bx1 : bx0;
  const float* __restrict__ bhv = role ? bh1 : bh0;
  const int KX = role ? HH : DD;   // K of the "x" operand
  const int nt = (KX + HH) >> 6;   // 12 (L0) or 16 (L1) K-tiles

  const int t = role ? (p - 1) : p;
  const int rd = (p + 1) & 1;  // buffer written during phase p-1
  const int wr = p & 1;
  const float* __restrict__ h0rd = h0buf + (size_t)rd * BB * HH;
  const float* __restrict__ h1rd = h1buf + (size_t)rd * BB * HH;
  float* __restrict__ hout = (role ? h1buf : h0buf) + (size_t)wr * BB * HH;

  auto srcload = [&](float4(&R)[8], int kt) {
    if (role == 0) {
      if (kt < 4)
        load_plain(R, xp + (size_t)t * DD + kt * 64, (size_t)TT * DD, trb, gq);
      else
        load_plain(R, h0rd + (kt - 4) * 64, (size_t)HH, trb, gq);
    } else {
      if (kt < 8) load_plain(R, h0rd + kt * 64, (size_t)HH, trb, gq);
      else        load_plain(R, h1rd + (kt - 8) * 64, (size_t)HH, trb, gq);
    }
  };

  float4 ra[8], rb4[8];
  srcload(ra, 0);  // issue first A tile ASAP (hides under W copy)

  // ---- stage W: linear float4 copy from pre-packed g_w ----
  {
    const float4* __restrict__ wsrc = (const float4*)(
        g_w + (role ? (W1_BASE + (size_t)bj * W1_BLK) : ((size_t)bj * W0_BLK)));
    float4* __restrict__ wdst = (float4*)Wl;
    const int n4 = (KX + HH) << 2;  // 3072 or 4096 float4s
    for (int i = tid; i < n4; i += 256) wdst[i] = wsrc[i];
  }

  float bg[4];
#pragma unroll
  for (int g = 0; g < 4; ++g)
    bg[g] = bxv[(size_t)g * HH + cell_g] + bhv[(size_t)g * HH + cell_g];

  // c-state: first step of this layer starts from 0
  const bool first = role ? (p == 1) : (p == 0);
  float cst0, cst1;
  {
    float* c0 = &g_c[((size_t)role * BB + rowg * 2 + 0) * HH + cell_g];
    float* c1 = &g_c[((size_t)role * BB + rowg * 2 + 1) * HH + cell_g];
    cst0 = first ? 0.0f : *c0;
    cst1 = first ? 0.0f : *c1;
  }

  float acc0[4] = {0.f, 0.f, 0.f, 0.f};
  float acc1[4] = {0.f, 0.f, 0.f, 0.f};

  srcload(rb4, 1);
  write_tile(Ab[0], ra, trb, wp_);
  __syncthreads();  // Wl + Ab[0] ready

#pragma unroll 1
  for (int kt = 0; kt < nt; kt += 2) {  // nt is even (12 or 16)
    if (kt + 2 < nt) srcload(ra, kt + 2);
    write_tile(Ab[1], rb4, trb, wp_);   // overlaps compute of buf0
    compute_tile(acc0, acc1, Ab[0], Wl, kt, rowg, cell);
    __syncthreads();                    // Ab[1] ready; buf0 readers done
    if (kt + 3 < nt) srcload(rb4, kt + 3);
    if (kt + 2 < nt) write_tile(Ab[0], ra, trb, wp_);  // overlaps buf1 compute
    compute_tile(acc0, acc1, Ab[1], Wl, kt + 1, rowg, cell);
    __syncthreads();                    // Ab[0] ready; buf1 readers done
  }

  // ---- cell update + h store (plain; kernel boundary publishes) ----
  {
    float iv = acc0[0] + bg[0], fv = acc0[1] + bg[1];
    float gv = acc0[2] + bg[2], ov = acc0[3] + bg[3];
    float cn = sig_(fv) * cst0 + sig_(iv) * tanhf(gv);
    g_c[((size_t)role * BB + rowg * 2 + 0) * HH + cell_g] = cn;
    hout[(size_t)(rowg * 2 + 0) * HH + cell_g] = sig_(ov) * tanhf(cn);
    iv = acc1[0] + bg[0]; fv = acc1[1] + bg[1];
    gv = acc1[2] + bg[2]; ov = acc1[3] + bg[3];
    cn = sig_(fv) * cst1 + sig_(iv) * tanhf(gv);
    g_c[((size_t)role * BB + rowg * 2 + 1) * HH + cell_g] = cn;
    hout[(size_t)(rowg * 2 + 1) * HH + cell_g] = sig_(ov) * tanhf(cn);
  }
}

// ---------------- head: out = relu(h1 @ fc1.T + b1) @ fc2.T + b2 ------------
__global__ __launch_bounds__(256) void head_kernel(const float* __restrict__ h1,
                                                   const float* __restrict__ fc1w,
                                                   const float* __restrict__ fc1b,
                                                   const float* __restrict__ fc2w,
                                                   const float* __restrict__ fc2b,
                                                   float* __restrict__ out) {
  __shared__ float part[256];
  __shared__ float hid[32];
  const int r = blockIdx.x;
  const int tid = threadIdx.x;
  const int c = tid & 31, pt = tid >> 5;
  const float4* ha = (const float4*)(h1 + (size_t)r * HH + pt * 64);
  const float4* wa = (const float4*)(fc1w + (size_t)c * HH + pt * 64);
  float s = 0.f;
#pragma unroll
  for (int j = 0; j < 16; ++j) {
    float4 av = ha[j], wv = wa[j];
    s = fmaf(av.x, wv.x, s);
    s = fmaf(av.y, wv.y, s);
    s = fmaf(av.z, wv.z, s);
    s = fmaf(av.w, wv.w, s);
  }
  part[tid] = s;
  __syncthreads();
  if (tid < 32) {
    float v = fc1b[tid];
#pragma unroll
    for (int q = 0; q < 8; ++q) v += part[q * 32 + tid];
    hid[tid] = fmaxf(v, 0.f);
  }
  __syncthreads();
  if (tid == 0) {
    float v = fc2b[0];
    for (int cc = 0; cc < 32; ++cc) v = fmaf(hid[cc], fc2w[cc], v);
    out[r] = v;
  }
}

extern "C" void kernel_launch(void* const* d_in, const int* in_sizes, int n_in,
                              void* d_out, int out_size, void* d_ws, size_t ws_size,
                              hipStream_t stream) {
  const float* x    = (const float*)d_in[0];
  const float* pw   = (const float*)d_in[1];
  const float* pb   = (const float*)d_in[2];
  const float* wx0  = (const float*)d_in[3];
  const float* bx0  = (const float*)d_in[4];
  const float* wh0  = (const float*)d_in[5];
  const float* bh0  = (const float*)d_in[6];
  const float* wx1  = (const float*)d_in[7];
  const float* bx1  = (const float*)d_in[8];
  const float* wh1  = (const float*)d_in[9];
  const float* bh1  = (const float*)d_in[10];
  const float* fc1w = (const float*)d_in[11];
  const float* fc1b = (const float*)d_in[12];
  const float* fc2w = (const float*)d_in[13];
  const float* fc2b = (const float*)d_in[14];
  float* out = (float*)d_out;

  // ws layout (floats): xp [B*T*D] | h0buf [2*B*H] | h1buf [2*B*H]
  // — EXACTLY the round-0/1/8 proven footprint, nothing appended.
  float* xp = (float*)d_ws;
  float* h0buf = xp + (size_t)BB * TT * DD;
  float* h1buf = h0buf + 2 * BB * HH;

  // zero initial h state (both buffers, both slots; 1 MB, stream-ordered)
  hipMemsetAsync(h0buf, 0, (size_t)4 * BB * HH * sizeof(float), stream);

  pack_w<<<dim3(256), dim3(256), 0, stream>>>(wx0, wh0, wx1, wh1);
  proj_kernel<<<dim3(4096), dim3(256), 0, stream>>>(x, pw, pb, xp);

  // 513 per-phase launches: kernel boundaries = grid barrier + coherence.
  for (int p = 0; p <= TT; ++p) {
    lstm_phase<<<dim3(256), dim3(256), 0, stream>>>(
        xp, bx0, bh0, bx1, bh1, h0buf, h1buf, p);
  }

  // final h1 lives in buffer index (512 & 1) == 0
  head_kernel<<<dim3(BB), dim3(256), 0, stream>>>(h1buf, fc1w, fc1b, fc2w, fc2b, out);
}